// Round 7
// baseline (770.706 us; speedup 1.0000x reference)
//
#include <hip/hip_runtime.h>
#include <stdint.h>

#define N_NODES 100000
#define N_EDGES 3200000
#define N_GRAPHS 512
#define DIM 128
#define M_PAD 100096          // N_NODES padded to multiple of 64
#define NGB (M_PAD / 256)     // 391 gemm blocks (256 rows each)
#define NBUCK 391             // buckets of 256 dst nodes: 391*256 = 100096 >= 100000
#define CAP 9216              // per-bucket region capacity; mean ~8184, sigma ~90
#define TILE 4096             // edges per block in k_bucket
#define NTILE 782             // ceil(3.2M / 4096)
#define XMM_NB 392            // stage-1 blocks for x min/max
#define NPOOL (8 * N_GRAPHS * 384)
#define NZB ((NPOOL + 255) / 256)   // 6144 zero blocks in k_init

typedef __bf16 bf16x8 __attribute__((ext_vector_type(8)));
typedef float f32x4 __attribute__((ext_vector_type(4)));

__device__ __forceinline__ unsigned short f2bf(float f) {
  unsigned u = __float_as_uint(f);
  u = u + 0x7FFFu + ((u >> 16) & 1u);      // round-to-nearest-even
  return (unsigned short)(u >> 16);
}
__device__ __forceinline__ float bflo(unsigned v) { return __uint_as_float(v << 16); }
__device__ __forceinline__ float bfhi(unsigned v) { return __uint_as_float(v & 0xFFFF0000u); }
__device__ __forceinline__ float bfs(unsigned short v) { return __uint_as_float(((unsigned)v) << 16); }
__device__ __forceinline__ unsigned packbf(float a, float b) {
  return (unsigned)f2bf(a) | ((unsigned)f2bf(b) << 16);
}

// ---------------- init: zeroing + W transpose/convert + coefficients (one launch) ----------------
__global__ void k_init(int* __restrict__ cnt, int* __restrict__ qbuf,
                       int* __restrict__ pooled,
                       const float* __restrict__ W1, const float* __restrict__ W2,
                       unsigned short* __restrict__ Wt1, unsigned short* __restrict__ Wt2,
                       const float* __restrict__ b1, const float* __restrict__ gamma,
                       const float* __restrict__ beta, const float* __restrict__ rmean,
                       const float* __restrict__ rvar, const float* __restrict__ b2,
                       float* __restrict__ sA1, float* __restrict__ sB1,
                       float* __restrict__ sB2) {
  int bid = blockIdx.x;
  if (bid < NZB) {
    int i = bid * 256 + threadIdx.x;
    if (i < NBUCK) cnt[i] = 0;
    if (i < 1024) qbuf[i] = 0;
    if (i < NPOOL) pooled[i] = 0;
    return;
  }
  if (bid < NZB + 192) {                       // W transpose+bf16: 192*256 = 3*DIM*DIM
    int i = (bid - NZB) * 256 + threadIdx.x;
    int l = i >> 14, rem = i & 16383, k = rem >> 7, n = rem & 127;
    int o = (l << 14) + (n << 7) + k;          // transposed: Wt[l][n][k]
    Wt1[o] = f2bf(W1[i]);
    Wt2[o] = f2bf(W2[i]);
    return;
  }
  for (int i = threadIdx.x; i < 3 * DIM; i += 256) {   // coefficients (sA2==1 dropped)
    float sa = gamma[i] * rsqrtf(rvar[i] + 1e-5f);
    sA1[i] = sa;
    sB1[i] = fmaf(sa, b1[i] - rmean[i], beta[i]);      // sa*(b1-rmean)+beta
    sB2[i] = b2[i];
  }
}

// ---------------- CSR build: tiled-reservation counting sort ----------------
__global__ __launch_bounds__(256) void k_bucket(const int* __restrict__ ei,
                                                int* __restrict__ cnt,
                                                unsigned* __restrict__ rec) {
  __shared__ int hist[NBUCK];
  __shared__ int curs[NBUCK];
  int t = threadIdx.x;
  int base_e = blockIdx.x * TILE;
  int es[16], ed[16];
#pragma unroll
  for (int k = 0; k < 16; ++k) {
    int e = base_e + k * 256 + t;
    if (e < N_EDGES) { es[k] = ei[e]; ed[k] = ei[N_EDGES + e]; }
    else ed[k] = -1;
  }
  for (int i = t; i < NBUCK; i += 256) hist[i] = 0;
  __syncthreads();
#pragma unroll
  for (int k = 0; k < 16; ++k)
    if (ed[k] >= 0) atomicAdd(&hist[ed[k] >> 8], 1);
  __syncthreads();
  for (int i = t; i < NBUCK; i += 256) {
    int h = hist[i];
    int g = h ? atomicAdd(&cnt[i], h) : 0;
    curs[i] = i * CAP + g;
  }
  __syncthreads();
#pragma unroll
  for (int k = 0; k < 16; ++k) {
    if (ed[k] >= 0) {
      int b = ed[k] >> 8;
      int pos = atomicAdd(&curs[b], 1);
      rec[pos] = ((unsigned)es[k] << 8) | (unsigned)(ed[k] & 255);
    }
  }
}

// bscan also finalizes xminf: xmm1 accumulated max(-x) >= 0 via atomicMax; true min = -that.
__global__ __launch_bounds__(512) void k_bscan(const int* __restrict__ cnt,
                                               int* __restrict__ bbase,
                                               int* __restrict__ row_ptr,
                                               float* __restrict__ xminf) {
  __shared__ int sc[512];
  int t = threadIdx.x;
  if (t < 128) xminf[t] = -xminf[t];
  int tot = (t < NBUCK) ? min(cnt[t], CAP) : 0;
  sc[t] = tot; __syncthreads();
  for (int off = 1; off < 512; off <<= 1) {
    int x = (t >= off) ? sc[t - off] : 0;
    __syncthreads();
    sc[t] += x;
    __syncthreads();
  }
  if (t < NBUCK) bbase[t] = sc[t] - tot;                 // exclusive
  if (t == NBUCK - 1) {
    bbase[NBUCK] = sc[t];
    row_ptr[N_NODES] = sc[t];                            // == N_EDGES
  }
}

__global__ __launch_bounds__(256) void k_build(const unsigned* __restrict__ rec,
                                               const int* __restrict__ cnt,
                                               const int* __restrict__ bbase,
                                               int* __restrict__ row_ptr,
                                               int* __restrict__ col) {
  __shared__ int hist[256];
  __shared__ int sc[256];
  __shared__ int curs[256];
  int b = blockIdx.x, t = threadIdx.x;
  int n = min(cnt[b], CAP);
  const unsigned* p = rec + (size_t)b * CAP;
  hist[t] = 0; __syncthreads();
  for (int i = t; i < n; i += 256) atomicAdd(&hist[p[i] & 255u], 1);
  __syncthreads();
  int v = hist[t];
  sc[t] = v; __syncthreads();
  for (int off = 1; off < 256; off <<= 1) {
    int x = (t >= off) ? sc[t - off] : 0;
    __syncthreads();
    sc[t] += x;
    __syncthreads();
  }
  int excl = bbase[b] + sc[t] - v;
  int node = (b << 8) + t;
  if (node < N_NODES) row_ptr[node] = excl;
  curs[t] = excl;
  __syncthreads();
  for (int i = t; i < n; i += 256) {
    unsigned w = p[i];
    int pos = atomicAdd(&curs[w & 255u], 1);
    col[pos] = (int)(w >> 8);
  }
}

// ---------------- x per-column range: block partials -> device atomicMax ----------------
// xmx[c] accumulates max(x,0); xminf[c] accumulates max(-x,0) (negated by k_bscan).
// Both >= 0 so int-compare atomicMax is order-preserving; qbuf pre-zeroed by k_init.
__global__ __launch_bounds__(256) void k_xmm1(const float* __restrict__ x,
                                              float* __restrict__ xmx,
                                              float* __restrict__ xminf) {
  __shared__ float smx[8][32][4];
  __shared__ float smn[8][32][4];
  int t = threadIdx.x;
  int c4 = t & 31;          // float4 column group
  int ro = t >> 5;          // 0..7
  float mx0 = 0.f, mx1 = 0.f, mx2 = 0.f, mx3 = 0.f;
  float mn0 = 0.f, mn1 = 0.f, mn2 = 0.f, mn3 = 0.f;
  for (int row = blockIdx.x * 8 + ro; row < N_NODES; row += XMM_NB * 8) {
    float4 v = ((const float4*)x)[(size_t)row * 32 + c4];
    mx0 = fmaxf(mx0, v.x); mn0 = fmaxf(mn0, -v.x);
    mx1 = fmaxf(mx1, v.y); mn1 = fmaxf(mn1, -v.y);
    mx2 = fmaxf(mx2, v.z); mn2 = fmaxf(mn2, -v.z);
    mx3 = fmaxf(mx3, v.w); mn3 = fmaxf(mn3, -v.w);
  }
  smx[ro][c4][0] = mx0; smx[ro][c4][1] = mx1; smx[ro][c4][2] = mx2; smx[ro][c4][3] = mx3;
  smn[ro][c4][0] = mn0; smn[ro][c4][1] = mn1; smn[ro][c4][2] = mn2; smn[ro][c4][3] = mn3;
  __syncthreads();
  for (int off = 4; off > 0; off >>= 1) {
    if (ro < off) {
#pragma unroll
      for (int k = 0; k < 4; ++k) {
        smx[ro][c4][k] = fmaxf(smx[ro][c4][k], smx[ro + off][c4][k]);
        smn[ro][c4][k] = fmaxf(smn[ro][c4][k], smn[ro + off][c4][k]);
      }
    }
    __syncthreads();
  }
  if (ro == 0) {
#pragma unroll
    for (int k = 0; k < 4; ++k) {
      atomicMax((int*)&xmx[c4 * 4 + k], __float_as_int(smx[0][c4][k]));
      atomicMax((int*)&xminf[c4 * 4 + k], __float_as_int(smn[0][c4][k]));
    }
  }
}

// ---------------- conversions ----------------
// vectorized x2: one float4 (4 dims) -> one u32 (4 u8) per thread
__global__ void k_convx(const float* __restrict__ x, const float* __restrict__ qmin,
                        const float* __restrict__ qmax, unsigned short* __restrict__ xq) {
  int j = blockIdx.x * 256 + threadIdx.x;
  if (j >= M_PAD * 32) return;
  int k = j & 31;            // float4 group within row
  int node = j >> 5;
  unsigned o = 0;
  if (node < N_NODES) {
    float4 f = ((const float4*)x)[j];
    float4 mn = ((const float4*)qmin)[k];
    float4 mx = ((const float4*)qmax)[k];
    float r0 = mx.x - mn.x, r1 = mx.y - mn.y, r2 = mx.z - mn.z, r3 = mx.w - mn.w;
    float is0 = r0 > 1e-20f ? 255.f / r0 : 0.f;
    float is1 = r1 > 1e-20f ? 255.f / r1 : 0.f;
    float is2 = r2 > 1e-20f ? 255.f / r2 : 0.f;
    float is3 = r3 > 1e-20f ? 255.f / r3 : 0.f;
    int q0 = (int)rintf((f.x - mn.x) * is0); q0 = min(max(q0, 0), 255);
    int q1 = (int)rintf((f.y - mn.y) * is1); q1 = min(max(q1, 0), 255);
    int q2 = (int)rintf((f.z - mn.z) * is2); q2 = min(max(q2, 0), 255);
    int q3 = (int)rintf((f.w - mn.w) * is3); q3 = min(max(q3, 0), 255);
    o = (unsigned)q0 | ((unsigned)q1 << 8) | ((unsigned)q2 << 16) | ((unsigned)q3 << 24);
  }
  ((unsigned*)xq)[j] = o;
}

__device__ __forceinline__ unsigned q1dw(unsigned v, float is0, float is1) {
  int q0 = (int)rintf(bflo(v) * is0); q0 = min(max(q0, 0), 255);
  int q1 = (int)rintf(bfhi(v) * is1); q1 = min(max(q1, 0), 255);
  return (unsigned)(q0 | (q1 << 8));
}

// h (bf16x2-packed) -> u8 (min = 0); vectorized x4 (uint4 in, uint2 out).
// Padding rows forced to ZERO so k_aggr can gather row N_NODES for masked tails.
__global__ void k_quant(const unsigned* __restrict__ hbf, const float* __restrict__ qmax,
                        unsigned short* __restrict__ hq) {
  int j = blockIdx.x * 256 + threadIdx.x;
  if (j >= M_PAD * 16) return;
  int node = j >> 4;
  uint2 o = make_uint2(0u, 0u);
  if (node < N_NODES) {
    int k = j & 15;                       // 8-dim group within row
    uint4 v = ((const uint4*)hbf)[j];
    float4 mxa = ((const float4*)qmax)[2 * k];
    float4 mxb = ((const float4*)qmax)[2 * k + 1];
    float ia0 = mxa.x > 1e-20f ? 255.f / mxa.x : 0.f;
    float ia1 = mxa.y > 1e-20f ? 255.f / mxa.y : 0.f;
    float ia2 = mxa.z > 1e-20f ? 255.f / mxa.z : 0.f;
    float ia3 = mxa.w > 1e-20f ? 255.f / mxa.w : 0.f;
    float ib0 = mxb.x > 1e-20f ? 255.f / mxb.x : 0.f;
    float ib1 = mxb.y > 1e-20f ? 255.f / mxb.y : 0.f;
    float ib2 = mxb.z > 1e-20f ? 255.f / mxb.z : 0.f;
    float ib3 = mxb.w > 1e-20f ? 255.f / mxb.w : 0.f;
    o.x = q1dw(v.x, ia0, ia1) | (q1dw(v.y, ia2, ia3) << 16);
    o.y = q1dw(v.z, ib0, ib1) | (q1dw(v.w, ib2, ib3) << 16);
  }
  ((uint2*)hq)[j] = o;
}

// ---------------- aggregation v4 (u8): dwordx4 gathers, 8 edges per VMEM instr ----------------
// v4 is the measured best (57 us).  Law from v4/v5/v6: dur = FETCH_SIZE / ~2.8-3.2 TB/s
// (scattered L2-fill ceiling, insensitive to ILP/occupancy); v4's FETCH (~158 MB) is
// within ~20% of the per-XCD compulsory floor for a random graph, so this stays.
__global__ __launch_bounds__(256) void k_aggr(const unsigned short* __restrict__ hq,
                                              const int* __restrict__ row_ptr,
                                              const int* __restrict__ col,
                                              const float* __restrict__ qmin,
                                              const float* __restrict__ qmax,
                                              unsigned* __restrict__ tmp) {
  const uint4* hq128 = (const uint4*)hq;     // one row = 8 uint4 (128 B)
  const unsigned* hq32 = (const unsigned*)hq;
  int wv = (blockIdx.x << 2) + (threadIdx.x >> 6);
  int lane = threadIdx.x & 63;
  int grp = lane >> 3;            // edge sub-slot 0..7
  int lo8 = lane & 7;             // which 16 B chunk of the row
  int dw = lane & 31;
  if (wv >= M_PAD) return;
  if (wv >= N_NODES) {
    ((uint2*)(tmp + (size_t)wv * 64))[dw] = make_uint2(0u, 0u);
    return;
  }
  // accumulators: chunk dword k -> ae{k} (dims 4k,4k+2 as u16x2), ao{k} (dims 4k+1,4k+3)
  unsigned ae0 = 0, ae1 = 0, ae2 = 0, ae3 = 0;
  unsigned ao0 = 0, ao1 = 0, ao2 = 0, ao3 = 0;
  int s = __builtin_amdgcn_readfirstlane(row_ptr[wv]);
  int e = __builtin_amdgcn_readfirstlane(row_ptr[wv + 1]);
  int pidx = (lo8 << 3) + grp;    // edge-in-chunk this lane preloads (valid when lo8 < 4)
  for (int base = s; base < e; base += 32) {
    int n = e - base; if (n > 32) n = 32;
    int cv = (pidx < n) ? col[base + pidx] : 0;
    // iteration j: lane gets col of edge 8j+grp  (src lane = (lane&0x38)|j)
    int s0 = __builtin_amdgcn_ds_swizzle(cv, 0x18);   // and=0x18, or=0
    int s1 = __builtin_amdgcn_ds_swizzle(cv, 0x38);   // or=1
    int s2 = __builtin_amdgcn_ds_swizzle(cv, 0x58);   // or=2
    int s3 = __builtin_amdgcn_ds_swizzle(cv, 0x78);   // or=3
    s0 = (grp      < n) ? s0 : N_NODES;
    s1 = (grp +  8 < n) ? s1 : N_NODES;
    s2 = (grp + 16 < n) ? s2 : N_NODES;
    s3 = (grp + 24 < n) ? s3 : N_NODES;
    uint4 v0 = hq128[s0 * 8 + lo8];
    uint4 v1 = hq128[s1 * 8 + lo8];
    uint4 v2 = hq128[s2 * 8 + lo8];
    uint4 v3 = hq128[s3 * 8 + lo8];
    ae0 += v0.x & 0x00FF00FFu; ao0 += (v0.x >> 8) & 0x00FF00FFu;
    ae1 += v0.y & 0x00FF00FFu; ao1 += (v0.y >> 8) & 0x00FF00FFu;
    ae2 += v0.z & 0x00FF00FFu; ao2 += (v0.z >> 8) & 0x00FF00FFu;
    ae3 += v0.w & 0x00FF00FFu; ao3 += (v0.w >> 8) & 0x00FF00FFu;
    ae0 += v1.x & 0x00FF00FFu; ao0 += (v1.x >> 8) & 0x00FF00FFu;
    ae1 += v1.y & 0x00FF00FFu; ao1 += (v1.y >> 8) & 0x00FF00FFu;
    ae2 += v1.z & 0x00FF00FFu; ao2 += (v1.z >> 8) & 0x00FF00FFu;
    ae3 += v1.w & 0x00FF00FFu; ao3 += (v1.w >> 8) & 0x00FF00FFu;
    ae0 += v2.x & 0x00FF00FFu; ao0 += (v2.x >> 8) & 0x00FF00FFu;
    ae1 += v2.y & 0x00FF00FFu; ao1 += (v2.y >> 8) & 0x00FF00FFu;
    ae2 += v2.z & 0x00FF00FFu; ao2 += (v2.z >> 8) & 0x00FF00FFu;
    ae3 += v2.w & 0x00FF00FFu; ao3 += (v2.w >> 8) & 0x00FF00FFu;
    ae0 += v3.x & 0x00FF00FFu; ao0 += (v3.x >> 8) & 0x00FF00FFu;
    ae1 += v3.y & 0x00FF00FFu; ao1 += (v3.y >> 8) & 0x00FF00FFu;
    ae2 += v3.z & 0x00FF00FFu; ao2 += (v3.z >> 8) & 0x00FF00FFu;
    ae3 += v3.w & 0x00FF00FFu; ao3 += (v3.w >> 8) & 0x00FF00FFu;
  }
  // reduce across the 8 edge-slots (lanes differing in bits 3..5)
  ae0 += __shfl_xor(ae0, 8); ae0 += __shfl_xor(ae0, 16); ae0 += __shfl_xor(ae0, 32);
  ae1 += __shfl_xor(ae1, 8); ae1 += __shfl_xor(ae1, 16); ae1 += __shfl_xor(ae1, 32);
  ae2 += __shfl_xor(ae2, 8); ae2 += __shfl_xor(ae2, 16); ae2 += __shfl_xor(ae2, 32);
  ae3 += __shfl_xor(ae3, 8); ae3 += __shfl_xor(ae3, 16); ae3 += __shfl_xor(ae3, 32);
  ao0 += __shfl_xor(ao0, 8); ao0 += __shfl_xor(ao0, 16); ao0 += __shfl_xor(ao0, 32);
  ao1 += __shfl_xor(ao1, 8); ao1 += __shfl_xor(ao1, 16); ao1 += __shfl_xor(ao1, 32);
  ao2 += __shfl_xor(ao2, 8); ao2 += __shfl_xor(ao2, 16); ao2 += __shfl_xor(ao2, 32);
  ao3 += __shfl_xor(ao3, 8); ao3 += __shfl_xor(ao3, 16); ao3 += __shfl_xor(ao3, 32);
  // redistribute to the 32-lane epilogue layout: lane dw wants dword k=dw&3 of chunk dw>>2
  {
    int ba = ((dw >> 2) & 7) << 2;  // byte addr of source lane (holds chunk dw>>2)
    unsigned f0 = (unsigned)__builtin_amdgcn_ds_bpermute(ba, (int)ae0);
    unsigned f1 = (unsigned)__builtin_amdgcn_ds_bpermute(ba, (int)ae1);
    unsigned f2 = (unsigned)__builtin_amdgcn_ds_bpermute(ba, (int)ae2);
    unsigned f3 = (unsigned)__builtin_amdgcn_ds_bpermute(ba, (int)ae3);
    unsigned g0 = (unsigned)__builtin_amdgcn_ds_bpermute(ba, (int)ao0);
    unsigned g1 = (unsigned)__builtin_amdgcn_ds_bpermute(ba, (int)ao1);
    unsigned g2 = (unsigned)__builtin_amdgcn_ds_bpermute(ba, (int)ao2);
    unsigned g3 = (unsigned)__builtin_amdgcn_ds_bpermute(ba, (int)ao3);
    unsigned el = (dw & 1) ? f1 : f0;
    unsigned eh = (dw & 1) ? f3 : f2;
    unsigned ae = (dw & 2) ? eh : el;
    unsigned ol = (dw & 1) ? g1 : g0;
    unsigned oh = (dw & 1) ? g3 : g2;
    unsigned ao = (dw & 2) ? oh : ol;
    if (lane < 32) {
      unsigned v = hq32[wv * 32 + dw];     // self term (eps=0: x + sum_neighbors)
      ae += v & 0x00FF00FFu;
      ao += (v >> 8) & 0x00FF00FFu;
      float cntf = (float)(e - s + 1);
      float4 qn = ((const float4*)qmin)[dw];
      float4 qx = ((const float4*)qmax)[dw];
      const float k255 = 1.0f / 255.0f;
      float A0 = fmaf(qn.x, cntf, (qx.x - qn.x) * k255 * (float)(ae & 0xFFFFu));
      float A1 = fmaf(qn.y, cntf, (qx.y - qn.y) * k255 * (float)(ao & 0xFFFFu));
      float A2 = fmaf(qn.z, cntf, (qx.z - qn.z) * k255 * (float)(ae >> 16));
      float A3 = fmaf(qn.w, cntf, (qx.w - qn.w) * k255 * (float)(ao >> 16));
      ((uint2*)(tmp + (size_t)wv * 64))[dw] = make_uint2(packbf(A0, A1), packbf(A2, A3));
    }
  }
}

// ---------------- fused layer v2: 32-row chunks, B-half splitting, occupancy 3/CU ----------------
// LDS halved (zt[4][32][136] = 35 KB) + Bf[4][4] (64 VGPR) -> launch_bounds(256,3).
// Pooling accumulators persist across the 2 chunks (row sequence per thread stays
// non-decreasing in graph id); same sums, flush granularity only.
__global__ __launch_bounds__(256, 3) void k_gemm12(const unsigned short* __restrict__ A,
                                                   const unsigned short* __restrict__ Wt1,
                                                   const float* __restrict__ sA1,
                                                   const float* __restrict__ sB1,
                                                   const unsigned short* __restrict__ Wt2,
                                                   const float* __restrict__ sB2,
                                                   const int* __restrict__ batch,
                                                   unsigned short* __restrict__ out,
                                                   float* __restrict__ pooled8, int layer,
                                                   float* __restrict__ hmax, int do_max) {
  __shared__ unsigned short zt[4][32][136];   // one 32-row chunk per wave
  __shared__ float colred[128];
  __shared__ int sgid[256];
  int w = threadIdx.x >> 6, lane = threadIdx.x & 63;
  int q = lane >> 4, n16 = lane & 15;
  if (do_max && threadIdx.x < 128) colred[threadIdx.x] = 0.f;
  {
    int rr = (blockIdx.x << 8) + threadIdx.x;
    sgid[threadIdx.x] = (rr < N_NODES) ? batch[rr] : -1;
  }
  __syncthreads();   // sgid (and colred) visible before cross-thread reads

  float mcol[8];
#pragma unroll
  for (int c = 0; c < 8; ++c) mcol[c] = 0.f;

  // pooling state persists across chunks
  int cp2 = threadIdx.x & 63;          // col pair: cols 2*cp2, 2*cp2+1
  int pgrp = threadIdx.x >> 6;         // rows pgrp*32..+31 within each 128-row chunk
  int cpy = blockIdx.x & 7;
  float pacc0 = 0.f, pacc1 = 0.f;
  int gcur = sgid[pgrp << 5];

#pragma unroll
  for (int ch = 0; ch < 2; ++ch) {
    int rbase = (blockIdx.x << 8) + (ch << 7) + (w << 5);

    // ---- phase 1: A from global, z -> LDS (2 tiles, B in 2 col-halves) ----
#pragma unroll
    for (int t = 0; t < 2; ++t) {
      bf16x8 a0, a1, a2, a3;
      {
        const unsigned short* ap = A + (size_t)(rbase + (t << 4) + n16) * DIM + q * 8;
        a0 = *(const bf16x8*)(ap);
        a1 = *(const bf16x8*)(ap + 32);
        a2 = *(const bf16x8*)(ap + 64);
        a3 = *(const bf16x8*)(ap + 96);
      }
      f32x4 acc[8] = {};
#pragma unroll
      for (int hf = 0; hf < 2; ++hf) {
        bf16x8 Bf[4][4];
#pragma unroll
        for (int ks = 0; ks < 4; ++ks)
#pragma unroll
          for (int c = 0; c < 4; ++c)
            Bf[ks][c] = *(const bf16x8*)(Wt1 + (size_t)(((hf * 4 + c) << 4) + n16) * DIM + ks * 32 + q * 8);
#pragma unroll
        for (int c = 0; c < 4; ++c)
          acc[hf * 4 + c] = __builtin_amdgcn_mfma_f32_16x16x32_bf16(a0, Bf[0][c], acc[hf * 4 + c], 0, 0, 0);
#pragma unroll
        for (int c = 0; c < 4; ++c)
          acc[hf * 4 + c] = __builtin_amdgcn_mfma_f32_16x16x32_bf16(a1, Bf[1][c], acc[hf * 4 + c], 0, 0, 0);
#pragma unroll
        for (int c = 0; c < 4; ++c)
          acc[hf * 4 + c] = __builtin_amdgcn_mfma_f32_16x16x32_bf16(a2, Bf[2][c], acc[hf * 4 + c], 0, 0, 0);
#pragma unroll
        for (int c = 0; c < 4; ++c)
          acc[hf * 4 + c] = __builtin_amdgcn_mfma_f32_16x16x32_bf16(a3, Bf[3][c], acc[hf * 4 + c], 0, 0, 0);
      }
#pragma unroll
      for (int c = 0; c < 8; ++c) {
        int colc = (c << 4) + n16;
        float s = sA1[colc], tt = sB1[colc];
#pragma unroll
        for (int r = 0; r < 4; ++r) {
          float v = fmaxf(fmaf(s, acc[c][r], tt), 0.0f);
          zt[w][(t << 4) + (q << 2) + r][colc] = f2bf(v);
        }
      }
    }

    // ---- phase 2: A (=z) from LDS, h -> LDS ----
#pragma unroll
    for (int t = 0; t < 2; ++t) {
      bf16x8 a0 = *(const bf16x8*)(&zt[w][(t << 4) + n16][q * 8]);
      bf16x8 a1 = *(const bf16x8*)(&zt[w][(t << 4) + n16][32 + q * 8]);
      bf16x8 a2 = *(const bf16x8*)(&zt[w][(t << 4) + n16][64 + q * 8]);
      bf16x8 a3 = *(const bf16x8*)(&zt[w][(t << 4) + n16][96 + q * 8]);
      f32x4 acc[8] = {};
#pragma unroll
      for (int hf = 0; hf < 2; ++hf) {
        bf16x8 Bf[4][4];
#pragma unroll
        for (int ks = 0; ks < 4; ++ks)
#pragma unroll
          for (int c = 0; c < 4; ++c)
            Bf[ks][c] = *(const bf16x8*)(Wt2 + (size_t)(((hf * 4 + c) << 4) + n16) * DIM + ks * 32 + q * 8);
#pragma unroll
        for (int c = 0; c < 4; ++c)
          acc[hf * 4 + c] = __builtin_amdgcn_mfma_f32_16x16x32_bf16(a0, Bf[0][c], acc[hf * 4 + c], 0, 0, 0);
#pragma unroll
        for (int c = 0; c < 4; ++c)
          acc[hf * 4 + c] = __builtin_amdgcn_mfma_f32_16x16x32_bf16(a1, Bf[1][c], acc[hf * 4 + c], 0, 0, 0);
#pragma unroll
        for (int c = 0; c < 4; ++c)
          acc[hf * 4 + c] = __builtin_amdgcn_mfma_f32_16x16x32_bf16(a2, Bf[2][c], acc[hf * 4 + c], 0, 0, 0);
#pragma unroll
        for (int c = 0; c < 4; ++c)
          acc[hf * 4 + c] = __builtin_amdgcn_mfma_f32_16x16x32_bf16(a3, Bf[3][c], acc[hf * 4 + c], 0, 0, 0);
      }
      // all LDS reads of tile t (z) must finish before overwriting with h
      asm volatile("s_waitcnt lgkmcnt(0)" ::: "memory");
#pragma unroll
      for (int c = 0; c < 8; ++c) {
        int colc = (c << 4) + n16;
        float tt = sB2[colc];
#pragma unroll
        for (int r = 0; r < 4; ++r) {
          float v = fmaxf(acc[c][r] + tt, 0.0f);    // sA2 == 1.0 always
          mcol[c] = fmaxf(mcol[c], v);
          zt[w][(t << 4) + (q << 2) + r][colc] = f2bf(v);
        }
      }
    }
    __syncthreads();   // h chunk visible to all threads

    // ---- bulk coalesced h store for this chunk (only when re-read by a later layer) ----
    if (do_max) {
      const unsigned short* ztf = &zt[0][0][0];
      int c16 = threadIdx.x & 15, rsub = threadIdx.x >> 4;
      unsigned short* ob = out + (size_t)((blockIdx.x << 8) + (ch << 7)) * DIM;
#pragma unroll
      for (int i = 0; i < 8; ++i) {
        int r = (i << 4) + rsub;             // 0..127 (chunk rows, contiguous in zt)
        *(uint4*)(ob + r * DIM + c16 * 8) = *(const uint4*)(ztf + r * 136 + c16 * 8);
      }
    }

    // ---- pooling over this chunk's 128 rows ----
    {
      const unsigned* ztu = (const unsigned*)&zt[0][0][0];   // 68 u32 per row
      for (int r = 0; r < 32; ++r) {
        int rowc = (pgrp << 5) + r;          // row within chunk, 0..127
        int g = sgid[(ch << 7) + rowc];
        if (g != gcur) {
          if (gcur >= 0) {
            float* bp = &pooled8[((size_t)cpy * N_GRAPHS + gcur) * 384 + layer * DIM + 2 * cp2];
            atomicAdd(bp, pacc0);
            atomicAdd(bp + 1, pacc1);
          }
          pacc0 = 0.f; pacc1 = 0.f; gcur = g;
        }
        if (g >= 0) {
          unsigned v = ztu[rowc * 68 + cp2];
          pacc0 += bflo(v);
          pacc1 += bfhi(v);
        }
      }
    }
    __syncthreads();   // pooling reads done before next chunk overwrites zt
  }

  if (gcur >= 0) {
    float* bp = &pooled8[((size_t)cpy * N_GRAPHS + gcur) * 384 + layer * DIM + 2 * cp2];
    atomicAdd(bp, pacc0);
    atomicAdd(bp + 1, pacc1);
  }

  if (do_max) {
#pragma unroll
    for (int c = 0; c < 8; ++c)
      atomicMax((int*)&colred[(c << 4) + n16], __float_as_int(mcol[c]));
    __syncthreads();
    if (threadIdx.x < 128)
      atomicMax((int*)&hmax[threadIdx.x], __float_as_int(colred[threadIdx.x]));
  }
}

// ---------------- head: 8 graphs per block, sums the 8 pooled copies ----------------
__global__ __launch_bounds__(384) void k_head(const float* __restrict__ pooled8,
                                              const float* __restrict__ Wfin,
                                              const float* __restrict__ bfin,
                                              const float* __restrict__ Wout,
                                              const float* __restrict__ bout,
                                              float* __restrict__ out) {
  __shared__ float p[8][384];
  __shared__ float hf[8][392];
  __shared__ float lg[8][10];
  __shared__ float lse[8];
  int t = threadIdx.x, g0 = blockIdx.x << 3;
  for (int i = t; i < 8 * 384; i += 384) {
    int gl = i / 384, k = i % 384;
    float s = 0.f;
#pragma unroll
    for (int cp = 0; cp < 8; ++cp)
      s += pooled8[((size_t)cp * N_GRAPHS + g0 + gl) * 384 + k];
    p[gl][k] = s;
  }
  __syncthreads();
  float bb = bfin[t];
  float acc[8];
#pragma unroll
  for (int g = 0; g < 8; ++g) acc[g] = bb;
  for (int k = 0; k < 384; ++k) {
    float wv = Wfin[k * 384 + t];
#pragma unroll
    for (int g = 0; g < 8; ++g) acc[g] = fmaf(p[g][k], wv, acc[g]);
  }
#pragma unroll
  for (int g = 0; g < 8; ++g) hf[g][t] = fmaxf(acc[g], 0.f);
  __syncthreads();
  if (t < 80) {
    int g = t / 10, c = t % 10;
    float a = bout[c];
    for (int k = 0; k < 384; ++k) a = fmaf(hf[g][k], Wout[k * 10 + c], a);
    lg[g][c] = a;
  }
  __syncthreads();
  if (t < 8) {
    float m = lg[t][0];
#pragma unroll
    for (int i = 1; i < 10; ++i) m = fmaxf(m, lg[t][i]);
    float ss = 0.f;
#pragma unroll
    for (int i = 0; i < 10; ++i) ss += __expf(lg[t][i] - m);
    lse[t] = m + __logf(ss);
  }
  __syncthreads();
  if (t < 80) {
    int g = t / 10, c = t % 10;
    out[(size_t)(g0 + g) * 10 + c] = lg[g][c];
    out[(size_t)N_GRAPHS * 10 + (size_t)(g0 + g) * 10 + c] = lg[g][c] - lse[g];
  }
}

extern "C" void kernel_launch(void* const* d_in, const int* in_sizes, int n_in,
                              void* d_out, int out_size, void* d_ws, size_t ws_size,
                              hipStream_t stream) {
  const float* x     = (const float*)d_in[0];
  const int*   ei    = (const int*)d_in[1];    // [2, N_EDGES]: src then dst
  const int*   batch = (const int*)d_in[2];
  const float* W1    = (const float*)d_in[4];
  const float* b1    = (const float*)d_in[5];
  const float* gamma = (const float*)d_in[6];
  const float* beta  = (const float*)d_in[7];
  const float* rmean = (const float*)d_in[8];
  const float* rvar  = (const float*)d_in[9];
  const float* W2    = (const float*)d_in[10];
  const float* b2    = (const float*)d_in[11];
  const float* Wfin  = (const float*)d_in[12];
  const float* bfin  = (const float*)d_in[13];
  const float* Wout  = (const float*)d_in[14];
  const float* bout  = (const float*)d_in[15];
  float* out = (float*)d_out;

  char* p = (char*)d_ws;
  auto alloc = [&](size_t bytes) { char* r = p; p += (bytes + 255) & ~255ull; return r; };
  int* cnt      = (int*)alloc(NBUCK * 4);
  unsigned* rec = (unsigned*)alloc((size_t)NBUCK * CAP * 4);
  int* bbase    = (int*)alloc((NBUCK + 1) * 4);
  int* row_ptr  = (int*)alloc((N_NODES + 1) * 4);
  int* colb     = (int*)alloc(((size_t)N_EDGES + 256) * 4);
  unsigned short* xq  = (unsigned short*)alloc((size_t)M_PAD * 64 * 2);
  unsigned short* hqb = (unsigned short*)alloc((size_t)M_PAD * 64 * 2);
  unsigned* hbf  = (unsigned*)alloc((size_t)M_PAD * 64 * 4);
  unsigned* tmpb = (unsigned*)alloc((size_t)M_PAD * 64 * 4);
  unsigned short* Wt1 = (unsigned short*)alloc(3 * DIM * DIM * 2);
  unsigned short* Wt2 = (unsigned short*)alloc(3 * DIM * DIM * 2);
  float* sA1    = (float*)alloc(384 * 4);
  float* sB1    = (float*)alloc(384 * 4);
  float* sB2    = (float*)alloc(384 * 4);
  float* qbuf   = (float*)alloc(1024 * 4);
  float* xmx    = qbuf + 128;    // max(v,0)
  float* xminf  = qbuf + 256;    // accumulates max(-v,0); negated to true min by k_bscan
  float* hmax0  = qbuf + 384;
  float* hmax1  = qbuf + 512;
  float* zeros  = qbuf + 640;    // 128 zeros (qmin for relu'd h)
  float* pooled8 = (float*)alloc((size_t)NPOOL * 4);

  // init: zero cnt/qbuf/pooled8 + W transpose/bf16 + coefficients (one launch)
  k_init<<<NZB + 193, 256, 0, stream>>>(cnt, (int*)qbuf, (int*)pooled8,
                                        W1, W2, Wt1, Wt2,
                                        b1, gamma, beta, rmean, rvar, b2,
                                        sA1, sB1, sB2);

  // x range (atomicMax into qbuf) must precede bscan's negation fixup
  k_xmm1<<<XMM_NB, 256, 0, stream>>>(x, xmx, xminf);

  // CSR build via tiled-reservation counting sort (edges constant across layers)
  k_bucket<<<NTILE, 256, 0, stream>>>(ei, cnt, rec);
  k_bscan<<<1, 512, 0, stream>>>(cnt, bbase, row_ptr, xminf);
  k_build<<<NBUCK, 256, 0, stream>>>(rec, cnt, bbase, row_ptr, colb);

  k_convx<<<(M_PAD * 32 + 255) / 256, 256, 0, stream>>>(x, xminf, xmx, xq);

  // layer 0
  k_aggr<<<M_PAD / 4, 256, 0, stream>>>(xq, row_ptr, colb, xminf, xmx, tmpb);
  k_gemm12<<<NGB, 256, 0, stream>>>((const unsigned short*)tmpb, Wt1, sA1, sB1,
                                    Wt2, sB2, batch, (unsigned short*)hbf,
                                    pooled8, 0, hmax0, 1);
  k_quant<<<(M_PAD * 16 + 255) / 256, 256, 0, stream>>>(hbf, hmax0, hqb);
  // layer 1
  k_aggr<<<M_PAD / 4, 256, 0, stream>>>(hqb, row_ptr, colb, zeros, hmax0, tmpb);
  k_gemm12<<<NGB, 256, 0, stream>>>((const unsigned short*)tmpb, Wt1 + DIM * DIM,
                                    sA1 + DIM, sB1 + DIM, Wt2 + DIM * DIM,
                                    sB2 + DIM, batch, (unsigned short*)hbf,
                                    pooled8, 1, hmax1, 1);
  k_quant<<<(M_PAD * 16 + 255) / 256, 256, 0, stream>>>(hbf, hmax1, hqb);
  // layer 2 (h never gathered again: no store/max/quant)
  k_aggr<<<M_PAD / 4, 256, 0, stream>>>(hqb, row_ptr, colb, zeros, hmax1, tmpb);
  k_gemm12<<<NGB, 256, 0, stream>>>((const unsigned short*)tmpb, Wt1 + 2 * DIM * DIM,
                                    sA1 + 2 * DIM, sB1 + 2 * DIM, Wt2 + 2 * DIM * DIM,
                                    sB2 + 2 * DIM, batch, (unsigned short*)hbf,
                                    pooled8, 2, hmax0, 0);

  k_head<<<N_GRAPHS / 8, 384, 0, stream>>>(pooled8, Wfin, bfin, Wout, bout, out);
}

// Round 8
// 574.327 us; speedup vs baseline: 1.3419x; 1.3419x over previous
//
#include <hip/hip_runtime.h>
#include <stdint.h>

#define N_NODES 100000
#define N_EDGES 3200000
#define N_GRAPHS 512
#define DIM 128
#define M_PAD 100096          // N_NODES padded to multiple of 64
#define NGB (M_PAD / 256)     // 391 gemm blocks (256 rows each)
#define NBUCK 391             // buckets of 256 dst nodes: 391*256 = 100096 >= 100000
#define CAP 9216              // per-bucket region capacity; mean ~8184, sigma ~90
#define TILE 4096             // edges per block in k_bucket
#define NTILE 782             // ceil(3.2M / 4096)
#define XMM_NB 392            // stage-1 blocks for x min/max
#define NPOOL (8 * N_GRAPHS * 384)
#define NZB ((NPOOL + 255) / 256)   // 6144 zero blocks in k_init

typedef __bf16 bf16x8 __attribute__((ext_vector_type(8)));
typedef float f32x4 __attribute__((ext_vector_type(4)));

__device__ __forceinline__ unsigned short f2bf(float f) {
  unsigned u = __float_as_uint(f);
  u = u + 0x7FFFu + ((u >> 16) & 1u);      // round-to-nearest-even
  return (unsigned short)(u >> 16);
}
__device__ __forceinline__ float bflo(unsigned v) { return __uint_as_float(v << 16); }
__device__ __forceinline__ float bfhi(unsigned v) { return __uint_as_float(v & 0xFFFF0000u); }
__device__ __forceinline__ float bfs(unsigned short v) { return __uint_as_float(((unsigned)v) << 16); }
__device__ __forceinline__ unsigned packbf(float a, float b) {
  return (unsigned)f2bf(a) | ((unsigned)f2bf(b) << 16);
}

// ---------------- init: zeroing + W transpose/convert + coefficients (one launch) ----------------
__global__ void k_init(int* __restrict__ cnt, int* __restrict__ qbuf,
                       int* __restrict__ pooled,
                       const float* __restrict__ W1, const float* __restrict__ W2,
                       unsigned short* __restrict__ Wt1, unsigned short* __restrict__ Wt2,
                       const float* __restrict__ b1, const float* __restrict__ gamma,
                       const float* __restrict__ beta, const float* __restrict__ rmean,
                       const float* __restrict__ rvar, const float* __restrict__ b2,
                       float* __restrict__ sA1, float* __restrict__ sB1,
                       float* __restrict__ sB2) {
  int bid = blockIdx.x;
  if (bid < NZB) {
    int i = bid * 256 + threadIdx.x;
    if (i < NBUCK) cnt[i] = 0;
    if (i < 1024) qbuf[i] = 0;
    if (i < NPOOL) pooled[i] = 0;
    return;
  }
  if (bid < NZB + 192) {                       // W transpose+bf16: 192*256 = 3*DIM*DIM
    int i = (bid - NZB) * 256 + threadIdx.x;
    int l = i >> 14, rem = i & 16383, k = rem >> 7, n = rem & 127;
    int o = (l << 14) + (n << 7) + k;          // transposed: Wt[l][n][k]
    Wt1[o] = f2bf(W1[i]);
    Wt2[o] = f2bf(W2[i]);
    return;
  }
  for (int i = threadIdx.x; i < 3 * DIM; i += 256) {   // coefficients (sA2==1 dropped)
    float sa = gamma[i] * rsqrtf(rvar[i] + 1e-5f);
    sA1[i] = sa;
    sB1[i] = fmaf(sa, b1[i] - rmean[i], beta[i]);      // sa*(b1-rmean)+beta
    sB2[i] = b2[i];
  }
}

// ---------------- CSR build: tiled-reservation counting sort ----------------
__global__ __launch_bounds__(256) void k_bucket(const int* __restrict__ ei,
                                                int* __restrict__ cnt,
                                                unsigned* __restrict__ rec) {
  __shared__ int hist[NBUCK];
  __shared__ int curs[NBUCK];
  int t = threadIdx.x;
  int base_e = blockIdx.x * TILE;
  int es[16], ed[16];
#pragma unroll
  for (int k = 0; k < 16; ++k) {
    int e = base_e + k * 256 + t;
    if (e < N_EDGES) { es[k] = ei[e]; ed[k] = ei[N_EDGES + e]; }
    else ed[k] = -1;
  }
  for (int i = t; i < NBUCK; i += 256) hist[i] = 0;
  __syncthreads();
#pragma unroll
  for (int k = 0; k < 16; ++k)
    if (ed[k] >= 0) atomicAdd(&hist[ed[k] >> 8], 1);
  __syncthreads();
  for (int i = t; i < NBUCK; i += 256) {
    int h = hist[i];
    int g = h ? atomicAdd(&cnt[i], h) : 0;
    curs[i] = i * CAP + g;
  }
  __syncthreads();
#pragma unroll
  for (int k = 0; k < 16; ++k) {
    if (ed[k] >= 0) {
      int b = ed[k] >> 8;
      int pos = atomicAdd(&curs[b], 1);
      rec[pos] = ((unsigned)es[k] << 8) | (unsigned)(ed[k] & 255);
    }
  }
}

// bscan also finalizes xminf: xmm1 accumulated max(-x) >= 0 via atomicMax; true min = -that.
__global__ __launch_bounds__(512) void k_bscan(const int* __restrict__ cnt,
                                               int* __restrict__ bbase,
                                               int* __restrict__ row_ptr,
                                               float* __restrict__ xminf) {
  __shared__ int sc[512];
  int t = threadIdx.x;
  if (t < 128) xminf[t] = -xminf[t];
  int tot = (t < NBUCK) ? min(cnt[t], CAP) : 0;
  sc[t] = tot; __syncthreads();
  for (int off = 1; off < 512; off <<= 1) {
    int x = (t >= off) ? sc[t - off] : 0;
    __syncthreads();
    sc[t] += x;
    __syncthreads();
  }
  if (t < NBUCK) bbase[t] = sc[t] - tot;                 // exclusive
  if (t == NBUCK - 1) {
    bbase[NBUCK] = sc[t];
    row_ptr[N_NODES] = sc[t];                            // == N_EDGES
  }
}

__global__ __launch_bounds__(256) void k_build(const unsigned* __restrict__ rec,
                                               const int* __restrict__ cnt,
                                               const int* __restrict__ bbase,
                                               int* __restrict__ row_ptr,
                                               int* __restrict__ col) {
  __shared__ int hist[256];
  __shared__ int sc[256];
  __shared__ int curs[256];
  int b = blockIdx.x, t = threadIdx.x;
  int n = min(cnt[b], CAP);
  const unsigned* p = rec + (size_t)b * CAP;
  hist[t] = 0; __syncthreads();
  for (int i = t; i < n; i += 256) atomicAdd(&hist[p[i] & 255u], 1);
  __syncthreads();
  int v = hist[t];
  sc[t] = v; __syncthreads();
  for (int off = 1; off < 256; off <<= 1) {
    int x = (t >= off) ? sc[t - off] : 0;
    __syncthreads();
    sc[t] += x;
    __syncthreads();
  }
  int excl = bbase[b] + sc[t] - v;
  int node = (b << 8) + t;
  if (node < N_NODES) row_ptr[node] = excl;
  curs[t] = excl;
  __syncthreads();
  for (int i = t; i < n; i += 256) {
    unsigned w = p[i];
    int pos = atomicAdd(&curs[w & 255u], 1);
    col[pos] = (int)(w >> 8);
  }
}

// ---------------- x per-column range: block partials -> device atomicMax ----------------
// xmx[c] accumulates max(x,0); xminf[c] accumulates max(-x,0) (negated by k_bscan).
// Both >= 0 so int-compare atomicMax is order-preserving; qbuf pre-zeroed by k_init.
__global__ __launch_bounds__(256) void k_xmm1(const float* __restrict__ x,
                                              float* __restrict__ xmx,
                                              float* __restrict__ xminf) {
  __shared__ float smx[8][32][4];
  __shared__ float smn[8][32][4];
  int t = threadIdx.x;
  int c4 = t & 31;          // float4 column group
  int ro = t >> 5;          // 0..7
  float mx0 = 0.f, mx1 = 0.f, mx2 = 0.f, mx3 = 0.f;
  float mn0 = 0.f, mn1 = 0.f, mn2 = 0.f, mn3 = 0.f;
  for (int row = blockIdx.x * 8 + ro; row < N_NODES; row += XMM_NB * 8) {
    float4 v = ((const float4*)x)[(size_t)row * 32 + c4];
    mx0 = fmaxf(mx0, v.x); mn0 = fmaxf(mn0, -v.x);
    mx1 = fmaxf(mx1, v.y); mn1 = fmaxf(mn1, -v.y);
    mx2 = fmaxf(mx2, v.z); mn2 = fmaxf(mn2, -v.z);
    mx3 = fmaxf(mx3, v.w); mn3 = fmaxf(mn3, -v.w);
  }
  smx[ro][c4][0] = mx0; smx[ro][c4][1] = mx1; smx[ro][c4][2] = mx2; smx[ro][c4][3] = mx3;
  smn[ro][c4][0] = mn0; smn[ro][c4][1] = mn1; smn[ro][c4][2] = mn2; smn[ro][c4][3] = mn3;
  __syncthreads();
  for (int off = 4; off > 0; off >>= 1) {
    if (ro < off) {
#pragma unroll
      for (int k = 0; k < 4; ++k) {
        smx[ro][c4][k] = fmaxf(smx[ro][c4][k], smx[ro + off][c4][k]);
        smn[ro][c4][k] = fmaxf(smn[ro][c4][k], smn[ro + off][c4][k]);
      }
    }
    __syncthreads();
  }
  if (ro == 0) {
#pragma unroll
    for (int k = 0; k < 4; ++k) {
      atomicMax((int*)&xmx[c4 * 4 + k], __float_as_int(smx[0][c4][k]));
      atomicMax((int*)&xminf[c4 * 4 + k], __float_as_int(smn[0][c4][k]));
    }
  }
}

// ---------------- conversions ----------------
// vectorized x2: one float4 (4 dims) -> one u32 (4 u8) per thread
__global__ void k_convx(const float* __restrict__ x, const float* __restrict__ qmin,
                        const float* __restrict__ qmax, unsigned short* __restrict__ xq) {
  int j = blockIdx.x * 256 + threadIdx.x;
  if (j >= M_PAD * 32) return;
  int k = j & 31;            // float4 group within row
  int node = j >> 5;
  unsigned o = 0;
  if (node < N_NODES) {
    float4 f = ((const float4*)x)[j];
    float4 mn = ((const float4*)qmin)[k];
    float4 mx = ((const float4*)qmax)[k];
    float r0 = mx.x - mn.x, r1 = mx.y - mn.y, r2 = mx.z - mn.z, r3 = mx.w - mn.w;
    float is0 = r0 > 1e-20f ? 255.f / r0 : 0.f;
    float is1 = r1 > 1e-20f ? 255.f / r1 : 0.f;
    float is2 = r2 > 1e-20f ? 255.f / r2 : 0.f;
    float is3 = r3 > 1e-20f ? 255.f / r3 : 0.f;
    int q0 = (int)rintf((f.x - mn.x) * is0); q0 = min(max(q0, 0), 255);
    int q1 = (int)rintf((f.y - mn.y) * is1); q1 = min(max(q1, 0), 255);
    int q2 = (int)rintf((f.z - mn.z) * is2); q2 = min(max(q2, 0), 255);
    int q3 = (int)rintf((f.w - mn.w) * is3); q3 = min(max(q3, 0), 255);
    o = (unsigned)q0 | ((unsigned)q1 << 8) | ((unsigned)q2 << 16) | ((unsigned)q3 << 24);
  }
  ((unsigned*)xq)[j] = o;
}

__device__ __forceinline__ unsigned q1dw(unsigned v, float is0, float is1) {
  int q0 = (int)rintf(bflo(v) * is0); q0 = min(max(q0, 0), 255);
  int q1 = (int)rintf(bfhi(v) * is1); q1 = min(max(q1, 0), 255);
  return (unsigned)(q0 | (q1 << 8));
}

// h (bf16x2-packed) -> u8 (min = 0); vectorized x4 (uint4 in, uint2 out).
// Padding rows forced to ZERO so k_aggr can gather row N_NODES for masked tails.
__global__ void k_quant(const unsigned* __restrict__ hbf, const float* __restrict__ qmax,
                        unsigned short* __restrict__ hq) {
  int j = blockIdx.x * 256 + threadIdx.x;
  if (j >= M_PAD * 16) return;
  int node = j >> 4;
  uint2 o = make_uint2(0u, 0u);
  if (node < N_NODES) {
    int k = j & 15;                       // 8-dim group within row
    uint4 v = ((const uint4*)hbf)[j];
    float4 mxa = ((const float4*)qmax)[2 * k];
    float4 mxb = ((const float4*)qmax)[2 * k + 1];
    float ia0 = mxa.x > 1e-20f ? 255.f / mxa.x : 0.f;
    float ia1 = mxa.y > 1e-20f ? 255.f / mxa.y : 0.f;
    float ia2 = mxa.z > 1e-20f ? 255.f / mxa.z : 0.f;
    float ia3 = mxa.w > 1e-20f ? 255.f / mxa.w : 0.f;
    float ib0 = mxb.x > 1e-20f ? 255.f / mxb.x : 0.f;
    float ib1 = mxb.y > 1e-20f ? 255.f / mxb.y : 0.f;
    float ib2 = mxb.z > 1e-20f ? 255.f / mxb.z : 0.f;
    float ib3 = mxb.w > 1e-20f ? 255.f / mxb.w : 0.f;
    o.x = q1dw(v.x, ia0, ia1) | (q1dw(v.y, ia2, ia3) << 16);
    o.y = q1dw(v.z, ib0, ib1) | (q1dw(v.w, ib2, ib3) << 16);
  }
  ((uint2*)hq)[j] = o;
}

// ---------------- aggregation v4 (u8): dwordx4 gathers, 8 edges per VMEM instr ----------------
// v4 is the measured best (57 us).  Law from v4/v5/v6: dur = FETCH_SIZE / ~2.8-3.2 TB/s
// (scattered L2-fill ceiling, insensitive to ILP/occupancy); v4's FETCH (~158 MB) is
// within ~20% of the per-XCD compulsory floor for a random graph, so this stays.
__global__ __launch_bounds__(256) void k_aggr(const unsigned short* __restrict__ hq,
                                              const int* __restrict__ row_ptr,
                                              const int* __restrict__ col,
                                              const float* __restrict__ qmin,
                                              const float* __restrict__ qmax,
                                              unsigned* __restrict__ tmp) {
  const uint4* hq128 = (const uint4*)hq;     // one row = 8 uint4 (128 B)
  const unsigned* hq32 = (const unsigned*)hq;
  int wv = (blockIdx.x << 2) + (threadIdx.x >> 6);
  int lane = threadIdx.x & 63;
  int grp = lane >> 3;            // edge sub-slot 0..7
  int lo8 = lane & 7;             // which 16 B chunk of the row
  int dw = lane & 31;
  if (wv >= M_PAD) return;
  if (wv >= N_NODES) {
    ((uint2*)(tmp + (size_t)wv * 64))[dw] = make_uint2(0u, 0u);
    return;
  }
  // accumulators: chunk dword k -> ae{k} (dims 4k,4k+2 as u16x2), ao{k} (dims 4k+1,4k+3)
  unsigned ae0 = 0, ae1 = 0, ae2 = 0, ae3 = 0;
  unsigned ao0 = 0, ao1 = 0, ao2 = 0, ao3 = 0;
  int s = __builtin_amdgcn_readfirstlane(row_ptr[wv]);
  int e = __builtin_amdgcn_readfirstlane(row_ptr[wv + 1]);
  int pidx = (lo8 << 3) + grp;    // edge-in-chunk this lane preloads (valid when lo8 < 4)
  for (int base = s; base < e; base += 32) {
    int n = e - base; if (n > 32) n = 32;
    int cv = (pidx < n) ? col[base + pidx] : 0;
    // iteration j: lane gets col of edge 8j+grp  (src lane = (lane&0x38)|j)
    int s0 = __builtin_amdgcn_ds_swizzle(cv, 0x18);   // and=0x18, or=0
    int s1 = __builtin_amdgcn_ds_swizzle(cv, 0x38);   // or=1
    int s2 = __builtin_amdgcn_ds_swizzle(cv, 0x58);   // or=2
    int s3 = __builtin_amdgcn_ds_swizzle(cv, 0x78);   // or=3
    s0 = (grp      < n) ? s0 : N_NODES;
    s1 = (grp +  8 < n) ? s1 : N_NODES;
    s2 = (grp + 16 < n) ? s2 : N_NODES;
    s3 = (grp + 24 < n) ? s3 : N_NODES;
    uint4 v0 = hq128[s0 * 8 + lo8];
    uint4 v1 = hq128[s1 * 8 + lo8];
    uint4 v2 = hq128[s2 * 8 + lo8];
    uint4 v3 = hq128[s3 * 8 + lo8];
    ae0 += v0.x & 0x00FF00FFu; ao0 += (v0.x >> 8) & 0x00FF00FFu;
    ae1 += v0.y & 0x00FF00FFu; ao1 += (v0.y >> 8) & 0x00FF00FFu;
    ae2 += v0.z & 0x00FF00FFu; ao2 += (v0.z >> 8) & 0x00FF00FFu;
    ae3 += v0.w & 0x00FF00FFu; ao3 += (v0.w >> 8) & 0x00FF00FFu;
    ae0 += v1.x & 0x00FF00FFu; ao0 += (v1.x >> 8) & 0x00FF00FFu;
    ae1 += v1.y & 0x00FF00FFu; ao1 += (v1.y >> 8) & 0x00FF00FFu;
    ae2 += v1.z & 0x00FF00FFu; ao2 += (v1.z >> 8) & 0x00FF00FFu;
    ae3 += v1.w & 0x00FF00FFu; ao3 += (v1.w >> 8) & 0x00FF00FFu;
    ae0 += v2.x & 0x00FF00FFu; ao0 += (v2.x >> 8) & 0x00FF00FFu;
    ae1 += v2.y & 0x00FF00FFu; ao1 += (v2.y >> 8) & 0x00FF00FFu;
    ae2 += v2.z & 0x00FF00FFu; ao2 += (v2.z >> 8) & 0x00FF00FFu;
    ae3 += v2.w & 0x00FF00FFu; ao3 += (v2.w >> 8) & 0x00FF00FFu;
    ae0 += v3.x & 0x00FF00FFu; ao0 += (v3.x >> 8) & 0x00FF00FFu;
    ae1 += v3.y & 0x00FF00FFu; ao1 += (v3.y >> 8) & 0x00FF00FFu;
    ae2 += v3.z & 0x00FF00FFu; ao2 += (v3.z >> 8) & 0x00FF00FFu;
    ae3 += v3.w & 0x00FF00FFu; ao3 += (v3.w >> 8) & 0x00FF00FFu;
  }
  // reduce across the 8 edge-slots (lanes differing in bits 3..5)
  ae0 += __shfl_xor(ae0, 8); ae0 += __shfl_xor(ae0, 16); ae0 += __shfl_xor(ae0, 32);
  ae1 += __shfl_xor(ae1, 8); ae1 += __shfl_xor(ae1, 16); ae1 += __shfl_xor(ae1, 32);
  ae2 += __shfl_xor(ae2, 8); ae2 += __shfl_xor(ae2, 16); ae2 += __shfl_xor(ae2, 32);
  ae3 += __shfl_xor(ae3, 8); ae3 += __shfl_xor(ae3, 16); ae3 += __shfl_xor(ae3, 32);
  ao0 += __shfl_xor(ao0, 8); ao0 += __shfl_xor(ao0, 16); ao0 += __shfl_xor(ao0, 32);
  ao1 += __shfl_xor(ao1, 8); ao1 += __shfl_xor(ao1, 16); ao1 += __shfl_xor(ao1, 32);
  ao2 += __shfl_xor(ao2, 8); ao2 += __shfl_xor(ao2, 16); ao2 += __shfl_xor(ao2, 32);
  ao3 += __shfl_xor(ao3, 8); ao3 += __shfl_xor(ao3, 16); ao3 += __shfl_xor(ao3, 32);
  // redistribute to the 32-lane epilogue layout: lane dw wants dword k=dw&3 of chunk dw>>2
  {
    int ba = ((dw >> 2) & 7) << 2;  // byte addr of source lane (holds chunk dw>>2)
    unsigned f0 = (unsigned)__builtin_amdgcn_ds_bpermute(ba, (int)ae0);
    unsigned f1 = (unsigned)__builtin_amdgcn_ds_bpermute(ba, (int)ae1);
    unsigned f2 = (unsigned)__builtin_amdgcn_ds_bpermute(ba, (int)ae2);
    unsigned f3 = (unsigned)__builtin_amdgcn_ds_bpermute(ba, (int)ae3);
    unsigned g0 = (unsigned)__builtin_amdgcn_ds_bpermute(ba, (int)ao0);
    unsigned g1 = (unsigned)__builtin_amdgcn_ds_bpermute(ba, (int)ao1);
    unsigned g2 = (unsigned)__builtin_amdgcn_ds_bpermute(ba, (int)ao2);
    unsigned g3 = (unsigned)__builtin_amdgcn_ds_bpermute(ba, (int)ao3);
    unsigned el = (dw & 1) ? f1 : f0;
    unsigned eh = (dw & 1) ? f3 : f2;
    unsigned ae = (dw & 2) ? eh : el;
    unsigned ol = (dw & 1) ? g1 : g0;
    unsigned oh = (dw & 1) ? g3 : g2;
    unsigned ao = (dw & 2) ? oh : ol;
    if (lane < 32) {
      unsigned v = hq32[wv * 32 + dw];     // self term (eps=0: x + sum_neighbors)
      ae += v & 0x00FF00FFu;
      ao += (v >> 8) & 0x00FF00FFu;
      float cntf = (float)(e - s + 1);
      float4 qn = ((const float4*)qmin)[dw];
      float4 qx = ((const float4*)qmax)[dw];
      const float k255 = 1.0f / 255.0f;
      float A0 = fmaf(qn.x, cntf, (qx.x - qn.x) * k255 * (float)(ae & 0xFFFFu));
      float A1 = fmaf(qn.y, cntf, (qx.y - qn.y) * k255 * (float)(ao & 0xFFFFu));
      float A2 = fmaf(qn.z, cntf, (qx.z - qn.z) * k255 * (float)(ae >> 16));
      float A3 = fmaf(qn.w, cntf, (qx.w - qn.w) * k255 * (float)(ao >> 16));
      ((uint2*)(tmp + (size_t)wv * 64))[dw] = make_uint2(packbf(A0, A1), packbf(A2, A3));
    }
  }
}

// ---------------- fused layer: GEMM1 -> GEMM2 -> pooling (B in regs, z/h in LDS) ----------------
// Round-6 proven version (v2's launch_bounds(256,3) spilled to scratch: VGPR cap 84 <
// live set ~130 -> WRITE_SIZE 105 MB, 110 us.  2 blocks/CU + full-width Bf is right.)
// phase-1: software-pipelined A loads; pooling: 4 row-groups x 64 iters, u32 reads.
__global__ __launch_bounds__(256, 2) void k_gemm12(const unsigned short* __restrict__ A,
                                                   const unsigned short* __restrict__ Wt1,
                                                   const float* __restrict__ sA1,
                                                   const float* __restrict__ sB1,
                                                   const unsigned short* __restrict__ Wt2,
                                                   const float* __restrict__ sB2,
                                                   const int* __restrict__ batch,
                                                   unsigned short* __restrict__ out,
                                                   float* __restrict__ pooled8, int layer,
                                                   float* __restrict__ hmax, int do_max) {
  __shared__ unsigned short zt[4][64][136];   // z then h, wave-private rows
  __shared__ float colred[128];
  __shared__ int sgid[256];
  int w = threadIdx.x >> 6, lane = threadIdx.x & 63;
  int q = lane >> 4, n16 = lane & 15;
  int rbase = (blockIdx.x << 8) + (w << 6);
  if (do_max && threadIdx.x < 128) colred[threadIdx.x] = 0.f;
  {
    int rr = (blockIdx.x << 8) + threadIdx.x;
    sgid[threadIdx.x] = (rr < N_NODES) ? batch[rr] : -1;
  }

  // ---- phase 1: B1 in registers, z -> LDS ----
  {
    bf16x8 Bf[4][8];
#pragma unroll
    for (int ks = 0; ks < 4; ++ks)
#pragma unroll
      for (int c = 0; c < 8; ++c)
        Bf[ks][c] = *(const bf16x8*)(Wt1 + (size_t)((c << 4) + n16) * DIM + ks * 32 + q * 8);
    bf16x8 an0, an1, an2, an3;
    {
      const unsigned short* ap = A + (size_t)(rbase + n16) * DIM + q * 8;
      an0 = *(const bf16x8*)(ap);
      an1 = *(const bf16x8*)(ap + 32);
      an2 = *(const bf16x8*)(ap + 64);
      an3 = *(const bf16x8*)(ap + 96);
    }
#pragma unroll
    for (int t = 0; t < 4; ++t) {
      bf16x8 a0 = an0, a1 = an1, a2 = an2, a3 = an3;
      if (t < 3) {   // prefetch next tile's A while computing this one
        const unsigned short* ap = A + (size_t)(rbase + ((t + 1) << 4) + n16) * DIM + q * 8;
        an0 = *(const bf16x8*)(ap);
        an1 = *(const bf16x8*)(ap + 32);
        an2 = *(const bf16x8*)(ap + 64);
        an3 = *(const bf16x8*)(ap + 96);
      }
      f32x4 acc[8] = {};
#pragma unroll
      for (int c = 0; c < 8; ++c) acc[c] = __builtin_amdgcn_mfma_f32_16x16x32_bf16(a0, Bf[0][c], acc[c], 0, 0, 0);
#pragma unroll
      for (int c = 0; c < 8; ++c) acc[c] = __builtin_amdgcn_mfma_f32_16x16x32_bf16(a1, Bf[1][c], acc[c], 0, 0, 0);
#pragma unroll
      for (int c = 0; c < 8; ++c) acc[c] = __builtin_amdgcn_mfma_f32_16x16x32_bf16(a2, Bf[2][c], acc[c], 0, 0, 0);
#pragma unroll
      for (int c = 0; c < 8; ++c) acc[c] = __builtin_amdgcn_mfma_f32_16x16x32_bf16(a3, Bf[3][c], acc[c], 0, 0, 0);
#pragma unroll
      for (int c = 0; c < 8; ++c) {
        int colc = (c << 4) + n16;
        float s = sA1[colc], tt = sB1[colc];
#pragma unroll
        for (int r = 0; r < 4; ++r) {
          float v = fmaxf(fmaf(s, acc[c][r], tt), 0.0f);
          zt[w][(t << 4) + (q << 2) + r][colc] = f2bf(v);
        }
      }
    }
  }

  // ---- phase 2: B2 in registers, A from LDS; h -> LDS ----
  float mcol[8];
#pragma unroll
  for (int c = 0; c < 8; ++c) mcol[c] = 0.f;
  {
    bf16x8 Bf[4][8];
#pragma unroll
    for (int ks = 0; ks < 4; ++ks)
#pragma unroll
      for (int c = 0; c < 8; ++c)
        Bf[ks][c] = *(const bf16x8*)(Wt2 + (size_t)((c << 4) + n16) * DIM + ks * 32 + q * 8);
#pragma unroll
    for (int t = 0; t < 4; ++t) {
      f32x4 acc[8] = {};
#pragma unroll
      for (int ks = 0; ks < 4; ++ks) {
        bf16x8 a = *(const bf16x8*)(&zt[w][(t << 4) + n16][ks * 32 + q * 8]);
#pragma unroll
        for (int c = 0; c < 8; ++c)
          acc[c] = __builtin_amdgcn_mfma_f32_16x16x32_bf16(a, Bf[ks][c], acc[c], 0, 0, 0);
      }
      // only LDS ordering needed: zt reads of tile t must finish before overwrite
      asm volatile("s_waitcnt lgkmcnt(0)" ::: "memory");
#pragma unroll
      for (int c = 0; c < 8; ++c) {
        int colc = (c << 4) + n16;
        float tt = sB2[colc];
#pragma unroll
        for (int r = 0; r < 4; ++r) {
          float v = fmaxf(acc[c][r] + tt, 0.0f);    // sA2 == 1.0 always
          mcol[c] = fmaxf(mcol[c], v);
          zt[w][(t << 4) + (q << 2) + r][colc] = f2bf(v);
        }
      }
    }
  }
  __syncthreads();   // h tiles + sgid visible to all

  // ---- bulk coalesced h store (only when a later layer re-reads h) ----
  if (do_max) {
    const unsigned short* ztf = &zt[0][0][0];
    int chunk = threadIdx.x & 15;          // 16 B chunk within a 256 B row
    int rsub  = threadIdx.x >> 4;          // 0..15
    unsigned short* ob = out + ((size_t)blockIdx.x << 8) * DIM;
#pragma unroll
    for (int i = 0; i < 16; ++i) {
      int r = (i << 4) + rsub;             // 0..255
      uint4 v = *(const uint4*)(ztf + r * 136 + chunk * 8);
      *(uint4*)(ob + r * DIM + chunk * 8) = v;
    }
  }

  // ---- pooling: segment-sum sorted rows, one atomic pair per (segment, col-pair) ----
  {
    const unsigned* ztu = (const unsigned*)&zt[0][0][0];   // 68 u32 per row
    int cp2 = threadIdx.x & 63;            // col pair: cols 2*cp2, 2*cp2+1
    int grp = threadIdx.x >> 6;            // 0..3, rows grp*64 .. grp*64+63
    int cpy = blockIdx.x & 7;
    float pacc0 = 0.f, pacc1 = 0.f;
    int gcur = sgid[grp << 6];
    for (int r = 0; r < 64; ++r) {
      int row = (grp << 6) + r;
      int g = sgid[row];
      if (g != gcur) {
        if (gcur >= 0) {
          float* bp = &pooled8[((size_t)cpy * N_GRAPHS + gcur) * 384 + layer * DIM + 2 * cp2];
          atomicAdd(bp, pacc0);
          atomicAdd(bp + 1, pacc1);
        }
        pacc0 = 0.f; pacc1 = 0.f; gcur = g;
      }
      if (g >= 0) {
        unsigned v = ztu[row * 68 + cp2];
        pacc0 += bflo(v);
        pacc1 += bfhi(v);
      }
    }
    if (gcur >= 0) {
      float* bp = &pooled8[((size_t)cpy * N_GRAPHS + gcur) * 384 + layer * DIM + 2 * cp2];
      atomicAdd(bp, pacc0);
      atomicAdd(bp + 1, pacc1);
    }
  }

  if (do_max) {
#pragma unroll
    for (int c = 0; c < 8; ++c)
      atomicMax((int*)&colred[(c << 4) + n16], __float_as_int(mcol[c]));
    __syncthreads();
    if (threadIdx.x < 128)
      atomicMax((int*)&hmax[threadIdx.x], __float_as_int(colred[threadIdx.x]));
  }
}

// ---------------- head: 8 graphs per block, sums the 8 pooled copies ----------------
__global__ __launch_bounds__(384) void k_head(const float* __restrict__ pooled8,
                                              const float* __restrict__ Wfin,
                                              const float* __restrict__ bfin,
                                              const float* __restrict__ Wout,
                                              const float* __restrict__ bout,
                                              float* __restrict__ out) {
  __shared__ float p[8][384];
  __shared__ float hf[8][392];
  __shared__ float lg[8][10];
  __shared__ float lse[8];
  int t = threadIdx.x, g0 = blockIdx.x << 3;
  for (int i = t; i < 8 * 384; i += 384) {
    int gl = i / 384, k = i % 384;
    float s = 0.f;
#pragma unroll
    for (int cp = 0; cp < 8; ++cp)
      s += pooled8[((size_t)cp * N_GRAPHS + g0 + gl) * 384 + k];
    p[gl][k] = s;
  }
  __syncthreads();
  float bb = bfin[t];
  float acc[8];
#pragma unroll
  for (int g = 0; g < 8; ++g) acc[g] = bb;
  for (int k = 0; k < 384; ++k) {
    float wv = Wfin[k * 384 + t];
#pragma unroll
    for (int g = 0; g < 8; ++g) acc[g] = fmaf(p[g][k], wv, acc[g]);
  }
#pragma unroll
  for (int g = 0; g < 8; ++g) hf[g][t] = fmaxf(acc[g], 0.f);
  __syncthreads();
  if (t < 80) {
    int g = t / 10, c = t % 10;
    float a = bout[c];
    for (int k = 0; k < 384; ++k) a = fmaf(hf[g][k], Wout[k * 10 + c], a);
    lg[g][c] = a;
  }
  __syncthreads();
  if (t < 8) {
    float m = lg[t][0];
#pragma unroll
    for (int i = 1; i < 10; ++i) m = fmaxf(m, lg[t][i]);
    float ss = 0.f;
#pragma unroll
    for (int i = 0; i < 10; ++i) ss += __expf(lg[t][i] - m);
    lse[t] = m + __logf(ss);
  }
  __syncthreads();
  if (t < 80) {
    int g = t / 10, c = t % 10;
    out[(size_t)(g0 + g) * 10 + c] = lg[g][c];
    out[(size_t)N_GRAPHS * 10 + (size_t)(g0 + g) * 10 + c] = lg[g][c] - lse[g];
  }
}

extern "C" void kernel_launch(void* const* d_in, const int* in_sizes, int n_in,
                              void* d_out, int out_size, void* d_ws, size_t ws_size,
                              hipStream_t stream) {
  const float* x     = (const float*)d_in[0];
  const int*   ei    = (const int*)d_in[1];    // [2, N_EDGES]: src then dst
  const int*   batch = (const int*)d_in[2];
  const float* W1    = (const float*)d_in[4];
  const float* b1    = (const float*)d_in[5];
  const float* gamma = (const float*)d_in[6];
  const float* beta  = (const float*)d_in[7];
  const float* rmean = (const float*)d_in[8];
  const float* rvar  = (const float*)d_in[9];
  const float* W2    = (const float*)d_in[10];
  const float* b2    = (const float*)d_in[11];
  const float* Wfin  = (const float*)d_in[12];
  const float* bfin  = (const float*)d_in[13];
  const float* Wout  = (const float*)d_in[14];
  const float* bout  = (const float*)d_in[15];
  float* out = (float*)d_out;

  char* p = (char*)d_ws;
  auto alloc = [&](size_t bytes) { char* r = p; p += (bytes + 255) & ~255ull; return r; };
  int* cnt      = (int*)alloc(NBUCK * 4);
  unsigned* rec = (unsigned*)alloc((size_t)NBUCK * CAP * 4);
  int* bbase    = (int*)alloc((NBUCK + 1) * 4);
  int* row_ptr  = (int*)alloc((N_NODES + 1) * 4);
  int* colb     = (int*)alloc(((size_t)N_EDGES + 256) * 4);
  unsigned short* xq  = (unsigned short*)alloc((size_t)M_PAD * 64 * 2);
  unsigned short* hqb = (unsigned short*)alloc((size_t)M_PAD * 64 * 2);
  unsigned* hbf  = (unsigned*)alloc((size_t)M_PAD * 64 * 4);
  unsigned* tmpb = (unsigned*)alloc((size_t)M_PAD * 64 * 4);
  unsigned short* Wt1 = (unsigned short*)alloc(3 * DIM * DIM * 2);
  unsigned short* Wt2 = (unsigned short*)alloc(3 * DIM * DIM * 2);
  float* sA1    = (float*)alloc(384 * 4);
  float* sB1    = (float*)alloc(384 * 4);
  float* sB2    = (float*)alloc(384 * 4);
  float* qbuf   = (float*)alloc(1024 * 4);
  float* xmx    = qbuf + 128;    // max(v,0)
  float* xminf  = qbuf + 256;    // accumulates max(-v,0); negated to true min by k_bscan
  float* hmax0  = qbuf + 384;
  float* hmax1  = qbuf + 512;
  float* zeros  = qbuf + 640;    // 128 zeros (qmin for relu'd h)
  float* pooled8 = (float*)alloc((size_t)NPOOL * 4);

  // init: zero cnt/qbuf/pooled8 + W transpose/bf16 + coefficients (one launch)
  k_init<<<NZB + 193, 256, 0, stream>>>(cnt, (int*)qbuf, (int*)pooled8,
                                        W1, W2, Wt1, Wt2,
                                        b1, gamma, beta, rmean, rvar, b2,
                                        sA1, sB1, sB2);

  // x range (atomicMax into qbuf) must precede bscan's negation fixup
  k_xmm1<<<XMM_NB, 256, 0, stream>>>(x, xmx, xminf);

  // CSR build via tiled-reservation counting sort (edges constant across layers)
  k_bucket<<<NTILE, 256, 0, stream>>>(ei, cnt, rec);
  k_bscan<<<1, 512, 0, stream>>>(cnt, bbase, row_ptr, xminf);
  k_build<<<NBUCK, 256, 0, stream>>>(rec, cnt, bbase, row_ptr, colb);

  k_convx<<<(M_PAD * 32 + 255) / 256, 256, 0, stream>>>(x, xminf, xmx, xq);

  // layer 0
  k_aggr<<<M_PAD / 4, 256, 0, stream>>>(xq, row_ptr, colb, xminf, xmx, tmpb);
  k_gemm12<<<NGB, 256, 0, stream>>>((const unsigned short*)tmpb, Wt1, sA1, sB1,
                                    Wt2, sB2, batch, (unsigned short*)hbf,
                                    pooled8, 0, hmax0, 1);
  k_quant<<<(M_PAD * 16 + 255) / 256, 256, 0, stream>>>(hbf, hmax0, hqb);
  // layer 1
  k_aggr<<<M_PAD / 4, 256, 0, stream>>>(hqb, row_ptr, colb, zeros, hmax0, tmpb);
  k_gemm12<<<NGB, 256, 0, stream>>>((const unsigned short*)tmpb, Wt1 + DIM * DIM,
                                    sA1 + DIM, sB1 + DIM, Wt2 + DIM * DIM,
                                    sB2 + DIM, batch, (unsigned short*)hbf,
                                    pooled8, 1, hmax1, 1);
  k_quant<<<(M_PAD * 16 + 255) / 256, 256, 0, stream>>>(hbf, hmax1, hqb);
  // layer 2 (h never gathered again: no store/max/quant)
  k_aggr<<<M_PAD / 4, 256, 0, stream>>>(hqb, row_ptr, colb, zeros, hmax1, tmpb);
  k_gemm12<<<NGB, 256, 0, stream>>>((const unsigned short*)tmpb, Wt1 + 2 * DIM * DIM,
                                    sA1 + 2 * DIM, sB1 + 2 * DIM, Wt2 + 2 * DIM * DIM,
                                    sB2 + 2 * DIM, batch, (unsigned short*)hbf,
                                    pooled8, 2, hmax0, 0);

  k_head<<<N_GRAPHS / 8, 384, 0, stream>>>(pooled8, Wfin, bfin, Wout, bout, out);
}